// Round 1
// baseline (1145.136 us; speedup 1.0000x reference)
//
#include <hip/hip_runtime.h>
#include <hip/hip_bf16.h>

// SlicedLMHead: logits[2048][32000] = H[2048][4096] @ W[32000][4096]^T + bias
// fp32 inputs cast to bf16 in-kernel (reg-staged), fp32 MFMA accumulate, fp32 out.
// Tile 128x128, BK=64, 4 waves (64x64 each), double-buffered LDS, XOR-swizzled.

typedef __attribute__((ext_vector_type(8))) short bhalf8;   // 8 bf16 (4 VGPRs)
typedef __attribute__((ext_vector_type(4))) float f32x4;    // MFMA acc
typedef __attribute__((ext_vector_type(8))) unsigned short us8;

#define M_DIM 2048
#define N_DIM 32000
#define K_DIM 4096
#define BM 128
#define BN 128
#define BK 64
#define NT (K_DIM / BK)   // 64 K-iterations
#define MBLKS (M_DIM / BM)  // 16
#define NBLKS (N_DIM / BN)  // 250

__device__ __forceinline__ unsigned short f2bf_rn(float f) {
    // round-to-nearest-even f32 -> bf16 (inputs are finite; no NaN path needed)
    unsigned int u = __float_as_uint(f);
    u += 0x7FFFu + ((u >> 16) & 1u);
    return (unsigned short)(u >> 16);
}

__global__ __launch_bounds__(256, 2)
void lmhead_gemm(const float* __restrict__ A,    // [2048][4096]
                 const float* __restrict__ W,    // [32000][4096]
                 const float* __restrict__ bias, // [32000]
                 float* __restrict__ C)          // [2048][32000]
{
    // LDS: bf16 tiles, row stride BK=64 elems = 128 B. 2*2*16KB = 64 KB.
    __shared__ unsigned short As[2][BM * BK];
    __shared__ unsigned short Bs[2][BN * BK];

    const int tid  = threadIdx.x;
    const int bid  = blockIdx.x;
    // M fastest-varying: resident blocks share few W panels -> W fetched ~once.
    const int mblk = bid & (MBLKS - 1);
    const int nblk = bid >> 4;

    // staging map: thread covers (row = s*32 + tid>>3, 8 consecutive k-floats at g=tid&7)
    const int st_row = tid >> 3;   // 0..31
    const int st_g   = tid & 7;    // 16B granule index (8 bf16 / 8 fp32*..2x float4)

    const int lane = tid & 63;
    const int wv   = tid >> 6;          // 4 waves: 2x2
    const int wm   = (wv >> 1) << 6;    // 0 or 64
    const int wn   = (wv & 1) << 6;     // 0 or 64
    const int l15  = lane & 15;
    const int l4   = lane >> 4;         // 0..3

    const float* aptr = A + (size_t)(mblk * BM + st_row) * K_DIM + st_g * 8;
    const float* bptr = W + (size_t)(nblk * BN + st_row) * K_DIM + st_g * 8;

    f32x4 acc[4][4] = {};
    float4 ra[4][2], rb[4][2];

    // ---- prologue: load + write tile 0 ----
    #pragma unroll
    for (int s = 0; s < 4; ++s) {
        const float* ap = aptr + (size_t)(s * 32) * K_DIM;
        const float* bp = bptr + (size_t)(s * 32) * K_DIM;
        ra[s][0] = *(const float4*)(ap);
        ra[s][1] = *(const float4*)(ap + 4);
        rb[s][0] = *(const float4*)(bp);
        rb[s][1] = *(const float4*)(bp + 4);
    }
    #pragma unroll
    for (int s = 0; s < 4; ++s) {
        const int row = s * 32 + st_row;
        const int off = row * BK + ((st_g ^ (row & 7)) << 3);
        us8 pa, pb;
        #pragma unroll
        for (int j = 0; j < 4; ++j) {
            pa[j]     = f2bf_rn(((const float*)&ra[s][0])[j]);
            pa[j + 4] = f2bf_rn(((const float*)&ra[s][1])[j]);
            pb[j]     = f2bf_rn(((const float*)&rb[s][0])[j]);
            pb[j + 4] = f2bf_rn(((const float*)&rb[s][1])[j]);
        }
        *(us8*)&As[0][off] = pa;
        *(us8*)&Bs[0][off] = pb;
    }
    __syncthreads();

    // ---- main loop: issue loads(t+1) -> compute(t) -> cvt+write(t+1) -> barrier ----
    for (int t = 0; t < NT; ++t) {
        const int cur = t & 1;
        const bool more = (t + 1) < NT;

        if (more) {
            const float* ap = aptr + (size_t)(t + 1) * BK;
            const float* bp = bptr + (size_t)(t + 1) * BK;
            #pragma unroll
            for (int s = 0; s < 4; ++s) {
                ra[s][0] = *(const float4*)(ap + (size_t)(s * 32) * K_DIM);
                ra[s][1] = *(const float4*)(ap + (size_t)(s * 32) * K_DIM + 4);
                rb[s][0] = *(const float4*)(bp + (size_t)(s * 32) * K_DIM);
                rb[s][1] = *(const float4*)(bp + (size_t)(s * 32) * K_DIM + 4);
            }
        }

        const unsigned short* as = As[cur];
        const unsigned short* bs = Bs[cur];
        #pragma unroll
        for (int kk = 0; kk < 2; ++kk) {
            bhalf8 af[4], bfv[4];
            #pragma unroll
            for (int mf = 0; mf < 4; ++mf) {
                const int row = wm + mf * 16 + l15;
                const int off = row * BK + ((((kk << 2) + l4) ^ (row & 7)) << 3);
                af[mf] = *(const bhalf8*)&as[off];
            }
            #pragma unroll
            for (int nf = 0; nf < 4; ++nf) {
                const int row = wn + nf * 16 + l15;
                const int off = row * BK + ((((kk << 2) + l4) ^ (row & 7)) << 3);
                bfv[nf] = *(const bhalf8*)&bs[off];
            }
            #pragma unroll
            for (int mf = 0; mf < 4; ++mf)
                #pragma unroll
                for (int nf = 0; nf < 4; ++nf)
                    acc[mf][nf] = __builtin_amdgcn_mfma_f32_16x16x32_bf16(
                        af[mf], bfv[nf], acc[mf][nf], 0, 0, 0);
        }

        if (more) {
            const int nbuf = cur ^ 1;
            #pragma unroll
            for (int s = 0; s < 4; ++s) {
                const int row = s * 32 + st_row;
                const int off = row * BK + ((st_g ^ (row & 7)) << 3);
                us8 pa, pb;
                #pragma unroll
                for (int j = 0; j < 4; ++j) {
                    pa[j]     = f2bf_rn(((const float*)&ra[s][0])[j]);
                    pa[j + 4] = f2bf_rn(((const float*)&ra[s][1])[j]);
                    pb[j]     = f2bf_rn(((const float*)&rb[s][0])[j]);
                    pb[j + 4] = f2bf_rn(((const float*)&rb[s][1])[j]);
                }
                *(us8*)&As[nbuf][off] = pa;
                *(us8*)&Bs[nbuf][off] = pb;
            }
        }
        __syncthreads();
    }

    // ---- epilogue: D lane map (16x16x32): row=(lane>>4)*4+r, col=lane&15 ----
    const size_t crow0 = (size_t)(mblk * BM + wm + l4 * 4);
    const int    ccol0 = nblk * BN + wn + l15;
    #pragma unroll
    for (int nf = 0; nf < 4; ++nf) {
        const float bv = bias[ccol0 + nf * 16];
        #pragma unroll
        for (int mf = 0; mf < 4; ++mf) {
            const size_t base = (crow0 + (size_t)mf * 16) * N_DIM + ccol0 + nf * 16;
            #pragma unroll
            for (int r = 0; r < 4; ++r) {
                C[base + (size_t)r * N_DIM] = acc[mf][nf][r] + bv;
            }
        }
    }
}

extern "C" void kernel_launch(void* const* d_in, const int* in_sizes, int n_in,
                              void* d_out, int out_size, void* d_ws, size_t ws_size,
                              hipStream_t stream) {
    const float* h = (const float*)d_in[0];
    const float* w = (const float*)d_in[1];
    const float* b = (const float*)d_in[2];
    float* out = (float*)d_out;
    // split_num (d_in[3]) is semantically a no-op: K-slices sum to the full GEMM.
    dim3 grid(MBLKS * NBLKS);  // 4000 blocks, M fastest-varying
    lmhead_gemm<<<grid, dim3(256), 0, stream>>>(h, w, b, out);
}

// Round 2
// 763.785 us; speedup vs baseline: 1.4993x; 1.4993x over previous
//
#include <hip/hip_runtime.h>
#include <hip/hip_bf16.h>

// SlicedLMHead: logits[2048][32000] = H[2048][4096] @ W[32000][4096]^T + bias
// Round 2: pre-convert W,H -> bf16 in d_ws (memory-bound pass), then m97-style
// GEMM: 128x128 tile, BK=64, global_load_lds(16B) staging, single LDS buffer,
// XOR-swizzled (pre-swizzled global source + swizzled ds_read), XCD swizzle.

typedef __attribute__((ext_vector_type(8))) short bhalf8;   // 8 bf16 (4 VGPRs)
typedef __attribute__((ext_vector_type(4))) float f32x4;    // MFMA acc
typedef __attribute__((ext_vector_type(8))) unsigned short us8;

#define M_DIM 2048
#define N_DIM 32000
#define K_DIM 4096
#define BM 128
#define BN 128
#define BK 64
#define NT (K_DIM / BK)     // 64 K-iterations
#define MBLKS (M_DIM / BM)  // 16
#define NBLKS (N_DIM / BN)  // 250
#define NWG   (MBLKS * NBLKS) // 4000, divisible by 8

#define W_ELEMS ((size_t)N_DIM * K_DIM)  // 131,072,000
#define H_ELEMS ((size_t)M_DIM * K_DIM)  // 8,388,608
#define WS_NEEDED ((W_ELEMS + H_ELEMS) * 2)

#define GLOAD_LDS16(g, l) \
    __builtin_amdgcn_global_load_lds( \
        (const __attribute__((address_space(1))) unsigned int*)(g), \
        (__attribute__((address_space(3))) unsigned int*)(l), 16, 0, 0)

__device__ __forceinline__ unsigned short f2bf_rn(float f) {
    unsigned int u = __float_as_uint(f);
    u += 0x7FFFu + ((u >> 16) & 1u);
    return (unsigned short)(u >> 16);
}

// ---------------- fp32 -> bf16 conversion pass (memory-bound) ----------------
__global__ __launch_bounds__(256)
void cvt_f32_bf16(const float* __restrict__ in, unsigned short* __restrict__ out,
                  size_t n8) {  // n8 = elems/8
    size_t i = (size_t)blockIdx.x * blockDim.x + threadIdx.x;
    const size_t stride = (size_t)gridDim.x * blockDim.x;
    for (; i < n8; i += stride) {
        const float4 v0 = ((const float4*)in)[i * 2];
        const float4 v1 = ((const float4*)in)[i * 2 + 1];
        us8 p;
        p[0] = f2bf_rn(v0.x); p[1] = f2bf_rn(v0.y);
        p[2] = f2bf_rn(v0.z); p[3] = f2bf_rn(v0.w);
        p[4] = f2bf_rn(v1.x); p[5] = f2bf_rn(v1.y);
        p[6] = f2bf_rn(v1.z); p[7] = f2bf_rn(v1.w);
        ((us8*)out)[i] = p;
    }
}

// ---------------- bf16 GEMM, m97 structure ----------------
__global__ __launch_bounds__(256, 3)
void lmhead_gemm_bf16(const unsigned short* __restrict__ A,  // [2048][4096] bf16
                      const unsigned short* __restrict__ W,  // [32000][4096] bf16
                      const float* __restrict__ bias,        // [32000]
                      float* __restrict__ C)                 // [2048][32000]
{
    __shared__ unsigned short As[BM * BK];  // 16 KB
    __shared__ unsigned short Bs[BN * BK];  // 16 KB

    const int tid = threadIdx.x;
    // XCD-chunked bijective swizzle (4000 % 8 == 0): each XCD gets a
    // contiguous wgid range -> all 16 m-blocks of a W panel on one XCD L2.
    const int bid  = blockIdx.x;
    const int wgid = (bid & 7) * (NWG / 8) + (bid >> 3);
    const int mblk = wgid & (MBLKS - 1);  // M fastest-varying
    const int nblk = wgid >> 4;

    const int lane = tid & 63;
    const int wv   = tid >> 6;          // 4 waves: 2x2 over the 128x128 tile
    const int wm   = (wv >> 1) << 6;    // 0 or 64
    const int wn   = (wv & 1) << 6;     // 0 or 64
    const int l15  = lane & 15;
    const int l4   = lane >> 4;         // 0..3

    // global_load_lds staging: per wave 4 issues for A, 4 for B.
    // Issue i covers LDS granules [(wv*4+i)*64 + lane] (granule = 16B = 8 bf16).
    // granule G -> row = G>>3, g = G&7; LDS is linear, so the global source is
    // PRE-SWIZZLED: lds[row][g] holds global granule g ^ (row&7).
    const int st_row = (lane >> 3);     // + (wv*4+i)*8
    const int st_g   = lane & 7;

    const unsigned short* srcA[4];
    const unsigned short* srcB[4];
    unsigned short* dstA[4];
    unsigned short* dstB[4];
    #pragma unroll
    for (int i = 0; i < 4; ++i) {
        const int row = (wv * 4 + i) * 8 + st_row;       // 0..127
        const int gsw = (st_g ^ (row & 7)) << 3;          // pre-swizzled k-offset
        srcA[i] = A + (size_t)(mblk * BM + row) * K_DIM + gsw;
        srcB[i] = W + (size_t)(nblk * BN + row) * K_DIM + gsw;
        dstA[i] = &As[(wv * 4 + i) * 512];                // wave-uniform base
        dstB[i] = &Bs[(wv * 4 + i) * 512];
    }

    f32x4 acc[4][4] = {};

    for (int t = 0; t < NT; ++t) {
        // ---- stage tile t (async DMA global->LDS) ----
        #pragma unroll
        for (int i = 0; i < 4; ++i) GLOAD_LDS16(srcA[i], dstA[i]);
        #pragma unroll
        for (int i = 0; i < 4; ++i) GLOAD_LDS16(srcB[i], dstB[i]);
        #pragma unroll
        for (int i = 0; i < 4; ++i) { srcA[i] += BK; srcB[i] += BK; }
        __syncthreads();  // compiler drains vmcnt(0) before barrier

        // ---- compute: 2 x (8 ds_read_b128 + 16 MFMA) ----
        #pragma unroll
        for (int kk = 0; kk < 2; ++kk) {
            bhalf8 af[4], bfv[4];
            #pragma unroll
            for (int mf = 0; mf < 4; ++mf) {
                const int row = wm + mf * 16 + l15;
                const int off = row * BK + ((((kk << 2) + l4) ^ (row & 7)) << 3);
                af[mf] = *(const bhalf8*)&As[off];
            }
            #pragma unroll
            for (int nf = 0; nf < 4; ++nf) {
                const int row = wn + nf * 16 + l15;
                const int off = row * BK + ((((kk << 2) + l4) ^ (row & 7)) << 3);
                bfv[nf] = *(const bhalf8*)&Bs[off];
            }
            #pragma unroll
            for (int mf = 0; mf < 4; ++mf)
                #pragma unroll
                for (int nf = 0; nf < 4; ++nf)
                    acc[mf][nf] = __builtin_amdgcn_mfma_f32_16x16x32_bf16(
                        af[mf], bfv[nf], acc[mf][nf], 0, 0, 0);
        }
        __syncthreads();  // reads done before next stage overwrites
    }

    // ---- epilogue: D lane map (16x16x32): row=(lane>>4)*4+r, col=lane&15 ----
    const size_t crow0 = (size_t)(mblk * BM + wm + l4 * 4);
    const int    ccol0 = nblk * BN + wn + l15;
    #pragma unroll
    for (int nf = 0; nf < 4; ++nf) {
        const float bv = bias[ccol0 + nf * 16];
        #pragma unroll
        for (int mf = 0; mf < 4; ++mf) {
            const size_t base = (crow0 + (size_t)mf * 16) * N_DIM + ccol0 + nf * 16;
            #pragma unroll
            for (int r = 0; r < 4; ++r)
                C[base + (size_t)r * N_DIM] = acc[mf][nf][r] + bv;
        }
    }
}

// ---------------- fallback (round-1, fp32 inputs, reg-staged) ----------------
__global__ __launch_bounds__(256, 2)
void lmhead_gemm_f32(const float* __restrict__ A, const float* __restrict__ W,
                     const float* __restrict__ bias, float* __restrict__ C) {
    __shared__ unsigned short As[2][BM * BK];
    __shared__ unsigned short Bs[2][BN * BK];

    const int tid  = threadIdx.x;
    const int bid  = blockIdx.x;
    const int mblk = bid & (MBLKS - 1);
    const int nblk = bid >> 4;
    const int st_row = tid >> 3;
    const int st_g   = tid & 7;
    const int lane = tid & 63;
    const int wv   = tid >> 6;
    const int wm   = (wv >> 1) << 6;
    const int wn   = (wv & 1) << 6;
    const int l15  = lane & 15;
    const int l4   = lane >> 4;

    const float* aptr = A + (size_t)(mblk * BM + st_row) * K_DIM + st_g * 8;
    const float* bptr = W + (size_t)(nblk * BN + st_row) * K_DIM + st_g * 8;

    f32x4 acc[4][4] = {};
    float4 ra[4][2], rb[4][2];

    #pragma unroll
    for (int s = 0; s < 4; ++s) {
        const float* ap = aptr + (size_t)(s * 32) * K_DIM;
        const float* bp = bptr + (size_t)(s * 32) * K_DIM;
        ra[s][0] = *(const float4*)(ap);
        ra[s][1] = *(const float4*)(ap + 4);
        rb[s][0] = *(const float4*)(bp);
        rb[s][1] = *(const float4*)(bp + 4);
    }
    #pragma unroll
    for (int s = 0; s < 4; ++s) {
        const int row = s * 32 + st_row;
        const int off = row * BK + ((st_g ^ (row & 7)) << 3);
        us8 pa, pb;
        #pragma unroll
        for (int j = 0; j < 4; ++j) {
            pa[j]     = f2bf_rn(((const float*)&ra[s][0])[j]);
            pa[j + 4] = f2bf_rn(((const float*)&ra[s][1])[j]);
            pb[j]     = f2bf_rn(((const float*)&rb[s][0])[j]);
            pb[j + 4] = f2bf_rn(((const float*)&rb[s][1])[j]);
        }
        *(us8*)&As[0][off] = pa;
        *(us8*)&Bs[0][off] = pb;
    }
    __syncthreads();

    for (int t = 0; t < NT; ++t) {
        const int cur = t & 1;
        const bool more = (t + 1) < NT;
        if (more) {
            const float* ap = aptr + (size_t)(t + 1) * BK;
            const float* bp = bptr + (size_t)(t + 1) * BK;
            #pragma unroll
            for (int s = 0; s < 4; ++s) {
                ra[s][0] = *(const float4*)(ap + (size_t)(s * 32) * K_DIM);
                ra[s][1] = *(const float4*)(ap + (size_t)(s * 32) * K_DIM + 4);
                rb[s][0] = *(const float4*)(bp + (size_t)(s * 32) * K_DIM);
                rb[s][1] = *(const float4*)(bp + (size_t)(s * 32) * K_DIM + 4);
            }
        }
        const unsigned short* as = As[cur];
        const unsigned short* bs = Bs[cur];
        #pragma unroll
        for (int kk = 0; kk < 2; ++kk) {
            bhalf8 af[4], bfv[4];
            #pragma unroll
            for (int mf = 0; mf < 4; ++mf) {
                const int row = wm + mf * 16 + l15;
                const int off = row * BK + ((((kk << 2) + l4) ^ (row & 7)) << 3);
                af[mf] = *(const bhalf8*)&as[off];
            }
            #pragma unroll
            for (int nf = 0; nf < 4; ++nf) {
                const int row = wn + nf * 16 + l15;
                const int off = row * BK + ((((kk << 2) + l4) ^ (row & 7)) << 3);
                bfv[nf] = *(const bhalf8*)&bs[off];
            }
            #pragma unroll
            for (int mf = 0; mf < 4; ++mf)
                #pragma unroll
                for (int nf = 0; nf < 4; ++nf)
                    acc[mf][nf] = __builtin_amdgcn_mfma_f32_16x16x32_bf16(
                        af[mf], bfv[nf], acc[mf][nf], 0, 0, 0);
        }
        if (more) {
            const int nbuf = cur ^ 1;
            #pragma unroll
            for (int s = 0; s < 4; ++s) {
                const int row = s * 32 + st_row;
                const int off = row * BK + ((st_g ^ (row & 7)) << 3);
                us8 pa, pb;
                #pragma unroll
                for (int j = 0; j < 4; ++j) {
                    pa[j]     = f2bf_rn(((const float*)&ra[s][0])[j]);
                    pa[j + 4] = f2bf_rn(((const float*)&ra[s][1])[j]);
                    pb[j]     = f2bf_rn(((const float*)&rb[s][0])[j]);
                    pb[j + 4] = f2bf_rn(((const float*)&rb[s][1])[j]);
                }
                *(us8*)&As[nbuf][off] = pa;
                *(us8*)&Bs[nbuf][off] = pb;
            }
        }
        __syncthreads();
    }

    const size_t crow0 = (size_t)(mblk * BM + wm + l4 * 4);
    const int    ccol0 = nblk * BN + wn + l15;
    #pragma unroll
    for (int nf = 0; nf < 4; ++nf) {
        const float bv = bias[ccol0 + nf * 16];
        #pragma unroll
        for (int mf = 0; mf < 4; ++mf) {
            const size_t base = (crow0 + (size_t)mf * 16) * N_DIM + ccol0 + nf * 16;
            #pragma unroll
            for (int r = 0; r < 4; ++r)
                C[base + (size_t)r * N_DIM] = acc[mf][nf][r] + bv;
        }
    }
}

extern "C" void kernel_launch(void* const* d_in, const int* in_sizes, int n_in,
                              void* d_out, int out_size, void* d_ws, size_t ws_size,
                              hipStream_t stream) {
    const float* h = (const float*)d_in[0];
    const float* w = (const float*)d_in[1];
    const float* b = (const float*)d_in[2];
    float* out = (float*)d_out;
    // split_num (d_in[3]) is semantically a no-op: K-slices sum to the full GEMM.

    if (ws_size >= WS_NEEDED) {
        unsigned short* wbf = (unsigned short*)d_ws;
        unsigned short* hbf = wbf + W_ELEMS;
        cvt_f32_bf16<<<2048, 256, 0, stream>>>(w, wbf, W_ELEMS / 8);
        cvt_f32_bf16<<<512, 256, 0, stream>>>(h, hbf, H_ELEMS / 8);
        lmhead_gemm_bf16<<<NWG, 256, 0, stream>>>(hbf, wbf, b, out);
    } else {
        lmhead_gemm_f32<<<NWG, 256, 0, stream>>>(h, w, b, out);
    }
}

// Round 3
// 629.507 us; speedup vs baseline: 1.8191x; 1.2133x over previous
//
#include <hip/hip_runtime.h>
#include <hip/hip_bf16.h>

// SlicedLMHead: logits[2048][32000] = H[2048][4096] @ W[32000][4096]^T + bias
// Round 3: cvt W,H -> bf16 in d_ws, then 256x256 8-phase GEMM (T2+T3+T4+T5):
// 512 thr / 8 waves (2Mx4N), BK=64, 128KB LDS double-buffered,
// global_load_lds(16B) w/ pre-swizzled source, counted vmcnt(4), setprio MFMA.

typedef __attribute__((ext_vector_type(8))) short bhalf8;   // 8 bf16
typedef __attribute__((ext_vector_type(4))) float f32x4;    // MFMA acc
typedef __attribute__((ext_vector_type(8))) unsigned short us8;

#define M_DIM 2048
#define N_DIM 32000
#define K_DIM 4096
#define BM 256
#define BN 256
#define BK 64
#define NT (K_DIM / BK)       // 64 K-tiles
#define MBLKS (M_DIM / BM)    // 8
#define NBLKS (N_DIM / BN)    // 125
#define NWG (MBLKS * NBLKS)   // 1000, divisible by 8

#define W_ELEMS ((size_t)N_DIM * K_DIM)
#define H_ELEMS ((size_t)M_DIM * K_DIM)
#define WS_NEEDED ((W_ELEMS + H_ELEMS) * 2)

#define GLOAD_LDS16(g, l) \
    __builtin_amdgcn_global_load_lds( \
        (const __attribute__((address_space(1))) unsigned int*)(g), \
        (__attribute__((address_space(3))) unsigned int*)(l), 16, 0, 0)

__device__ __forceinline__ unsigned short f2bf_rn(float f) {
    unsigned int u = __float_as_uint(f);
    u += 0x7FFFu + ((u >> 16) & 1u);
    return (unsigned short)(u >> 16);
}

// ---------------- fp32 -> bf16 conversion pass (memory-bound) ----------------
__global__ __launch_bounds__(256)
void cvt_f32_bf16(const float* __restrict__ in, unsigned short* __restrict__ out,
                  size_t n8) {
    size_t i = (size_t)blockIdx.x * blockDim.x + threadIdx.x;
    const size_t stride = (size_t)gridDim.x * blockDim.x;
    for (; i < n8; i += stride) {
        const float4 v0 = ((const float4*)in)[i * 2];
        const float4 v1 = ((const float4*)in)[i * 2 + 1];
        us8 p;
        p[0] = f2bf_rn(v0.x); p[1] = f2bf_rn(v0.y);
        p[2] = f2bf_rn(v0.z); p[3] = f2bf_rn(v0.w);
        p[4] = f2bf_rn(v1.x); p[5] = f2bf_rn(v1.y);
        p[6] = f2bf_rn(v1.z); p[7] = f2bf_rn(v1.w);
        ((us8*)out)[i] = p;
    }
}

// ---------------- 256^2 8-phase bf16 GEMM ----------------
// LDS map (elems): A half (b,h) at (b*2+h)*8192 ; B half at 32768 + (b*2+h)*8192.
// Granule swizzle: lds[row][g] holds global granule g ^ (row&7) (granule = 8 bf16).
// Issue stream per K-tile t: ph0 B(t+1,top), ph1 B(t+1,bot), ph3 A(t+2,top+bot).
// vmcnt(4) at each tile end leaves exactly A(t+2)'s 4 loads in flight.
__global__ __launch_bounds__(512, 2)
void lmhead_gemm_256(const unsigned short* __restrict__ A,  // [2048][4096] bf16
                     const unsigned short* __restrict__ W,  // [32000][4096] bf16
                     const float* __restrict__ bias,
                     float* __restrict__ C)
{
    __shared__ unsigned short lds[65536];  // 128 KB

    const int tid  = threadIdx.x;
    const int bid  = blockIdx.x;
    const int wgid = (bid & 7) * (NWG / 8) + (bid >> 3);  // bijective XCD chunks
    const int mblk = wgid & (MBLKS - 1);                  // M fastest-varying
    const int nblk = wgid >> 3;

    const int lane = tid & 63;
    const int wv   = tid >> 6;     // 0..7
    const int wr   = wv >> 2;      // 0..1 : wave M-half (128 rows)
    const int wc   = wv & 3;       // 0..3 : wave N-slot (64 cols)
    const int l15  = lane & 15;
    const int l4   = lane >> 4;

    // ---- staging addressing (per thread) ----
    const int strow = tid >> 3;                               // 0..63
    const int sgsw  = ((tid & 7) ^ (strow & 7)) << 3;         // pre-swizzled k-off
    const unsigned short* const srcA = A + (size_t)(mblk * BM + strow) * K_DIM + sgsw;
    const unsigned short* const srcB = W + (size_t)(nblk * BN + strow) * K_DIM + sgsw;
    const int dstw = (tid & 448) * 8;                         // wave-uniform LDS base

#define STAGE_A(u, h) { \
        const unsigned short* s_ = srcA + (size_t)((h) * 128) * K_DIM + (size_t)(u) * BK; \
        unsigned short* d_ = &lds[((((u) & 1) * 2 + (h)) * 8192) + dstw]; \
        GLOAD_LDS16(s_, d_); GLOAD_LDS16(s_ + (size_t)64 * K_DIM, d_ + 4096); }
#define STAGE_B(u, h) { \
        const unsigned short* s_ = srcB + (size_t)((h) * 128) * K_DIM + (size_t)(u) * BK; \
        unsigned short* d_ = &lds[32768 + ((((u) & 1) * 2 + (h)) * 8192) + dstw]; \
        GLOAD_LDS16(s_, d_); GLOAD_LDS16(s_ + (size_t)64 * K_DIM, d_ + 4096); }

    // ---- ds_read addressing (per thread) ----
    const int swz0  = (l4 ^ (l15 & 7)) << 3;          // kk=0 swizzled granule
    const int swz1  = ((4 + l4) ^ (l15 & 7)) << 3;    // kk=1
    const int aoff0 = l15 * 64 + swz0;
    const int aoff1 = l15 * 64 + swz1;
    const int boff0 = ((wc & 1) * 64 + l15) * 64 + swz0;
    const int boff1 = ((wc & 1) * 64 + l15) * 64 + swz1;

    f32x4 acc[8][4] = {};
    bhalf8 af0[4][2], af1[4][2], bf[4][2];

    // ---- prologue: A(0), B(0), A(1) = 12 loads; tile0 landed, A(1) in flight ----
    STAGE_A(0, 0); STAGE_A(0, 1);
    STAGE_B(0, 0); STAGE_B(0, 1);
    STAGE_A(1, 0); STAGE_A(1, 1);
    asm volatile("s_waitcnt vmcnt(4)" ::: "memory");
    __builtin_amdgcn_sched_barrier(0);
    __builtin_amdgcn_s_barrier();

    for (int t = 0; t < NT; ++t) {
        const int b = t & 1;
        const unsigned short* asb = &lds[(b * 2 + wr) * 8192];
        const unsigned short* bsb = &lds[32768 + (b * 2 + (wc >> 1)) * 8192];

        // ===== phase 0: read af0(8)+bf[0..1](4); stage B(t+1,top); MFMA q(0,0) =====
        #pragma unroll
        for (int mf = 0; mf < 4; ++mf) {
            af0[mf][0] = *(const bhalf8*)&asb[aoff0 + mf * 1024];
            af0[mf][1] = *(const bhalf8*)&asb[aoff1 + mf * 1024];
        }
        #pragma unroll
        for (int nf = 0; nf < 2; ++nf) {
            bf[nf][0] = *(const bhalf8*)&bsb[boff0 + nf * 1024];
            bf[nf][1] = *(const bhalf8*)&bsb[boff1 + nf * 1024];
        }
        if (t + 1 < NT) STAGE_B(t + 1, 0);
        __builtin_amdgcn_sched_barrier(0);
        __builtin_amdgcn_s_barrier();
        asm volatile("s_waitcnt lgkmcnt(0)" ::: "memory");
        __builtin_amdgcn_sched_barrier(0);
        __builtin_amdgcn_s_setprio(1);
        #pragma unroll
        for (int mf = 0; mf < 4; ++mf)
            #pragma unroll
            for (int nf = 0; nf < 2; ++nf)
                #pragma unroll
                for (int kk = 0; kk < 2; ++kk)
                    acc[mf][nf] = __builtin_amdgcn_mfma_f32_16x16x32_bf16(
                        af0[mf][kk], bf[nf][kk], acc[mf][nf], 0, 0, 0);
        __builtin_amdgcn_s_setprio(0);
        __builtin_amdgcn_s_barrier();

        // ===== phase 1: read bf[2..3](4); stage B(t+1,bot); MFMA q(0,1) =====
        #pragma unroll
        for (int nf = 0; nf < 2; ++nf) {
            bf[2 + nf][0] = *(const bhalf8*)&bsb[boff0 + (2 + nf) * 1024];
            bf[2 + nf][1] = *(const bhalf8*)&bsb[boff1 + (2 + nf) * 1024];
        }
        if (t + 1 < NT) STAGE_B(t + 1, 1);
        __builtin_amdgcn_sched_barrier(0);
        __builtin_amdgcn_s_barrier();
        asm volatile("s_waitcnt lgkmcnt(0)" ::: "memory");
        __builtin_amdgcn_sched_barrier(0);
        __builtin_amdgcn_s_setprio(1);
        #pragma unroll
        for (int mf = 0; mf < 4; ++mf)
            #pragma unroll
            for (int nf = 0; nf < 2; ++nf)
                #pragma unroll
                for (int kk = 0; kk < 2; ++kk)
                    acc[mf][2 + nf] = __builtin_amdgcn_mfma_f32_16x16x32_bf16(
                        af0[mf][kk], bf[2 + nf][kk], acc[mf][2 + nf], 0, 0, 0);
        __builtin_amdgcn_s_setprio(0);
        __builtin_amdgcn_s_barrier();

        // ===== phase 2: read af1(8); MFMA q(1,1) =====
        #pragma unroll
        for (int mf = 0; mf < 4; ++mf) {
            af1[mf][0] = *(const bhalf8*)&asb[aoff0 + 4096 + mf * 1024];
            af1[mf][1] = *(const bhalf8*)&asb[aoff1 + 4096 + mf * 1024];
        }
        __builtin_amdgcn_sched_barrier(0);
        __builtin_amdgcn_s_barrier();
        asm volatile("s_waitcnt lgkmcnt(0)" ::: "memory");
        __builtin_amdgcn_sched_barrier(0);
        __builtin_amdgcn_s_setprio(1);
        #pragma unroll
        for (int mf = 0; mf < 4; ++mf)
            #pragma unroll
            for (int nf = 0; nf < 2; ++nf)
                #pragma unroll
                for (int kk = 0; kk < 2; ++kk)
                    acc[4 + mf][2 + nf] = __builtin_amdgcn_mfma_f32_16x16x32_bf16(
                        af1[mf][kk], bf[2 + nf][kk], acc[4 + mf][2 + nf], 0, 0, 0);
        __builtin_amdgcn_s_setprio(0);
        __builtin_amdgcn_s_barrier();

        // ===== phase 3: stage A(t+2) both halves; MFMA q(1,0); counted vmcnt =====
        if (t + 2 < NT) { STAGE_A(t + 2, 0); STAGE_A(t + 2, 1); }
        __builtin_amdgcn_sched_barrier(0);
        __builtin_amdgcn_s_barrier();
        __builtin_amdgcn_s_setprio(1);
        #pragma unroll
        for (int mf = 0; mf < 4; ++mf)
            #pragma unroll
            for (int nf = 0; nf < 2; ++nf)
                #pragma unroll
                for (int kk = 0; kk < 2; ++kk)
                    acc[4 + mf][nf] = __builtin_amdgcn_mfma_f32_16x16x32_bf16(
                        af1[mf][kk], bf[nf][kk], acc[4 + mf][nf], 0, 0, 0);
        __builtin_amdgcn_s_setprio(0);
        if (t < NT - 2) { asm volatile("s_waitcnt vmcnt(4)" ::: "memory"); }
        else            { asm volatile("s_waitcnt vmcnt(0)" ::: "memory"); }
        __builtin_amdgcn_sched_barrier(0);
        __builtin_amdgcn_s_barrier();
    }

    // ---- epilogue: D map row=(lane>>4)*4+r, col=lane&15 ----
    const size_t crow0 = (size_t)(mblk * BM + wr * 128 + l4 * 4);
    const int    ccol0 = nblk * BN + wc * 64 + l15;
    #pragma unroll
    for (int jn = 0; jn < 4; ++jn) {
        const float bv = bias[ccol0 + jn * 16];
        #pragma unroll
        for (int i = 0; i < 8; ++i) {
            const size_t base = (crow0 + (size_t)i * 16) * N_DIM + ccol0 + jn * 16;
            #pragma unroll
            for (int r = 0; r < 4; ++r)
                C[base + (size_t)r * N_DIM] = acc[i][jn][r] + bv;
        }
    }
#undef STAGE_A
#undef STAGE_B
}

// ---------------- fallback (fp32 inputs, reg-staged 128^2) ----------------
__global__ __launch_bounds__(256, 2)
void lmhead_gemm_f32(const float* __restrict__ A, const float* __restrict__ W,
                     const float* __restrict__ bias, float* __restrict__ C) {
    __shared__ unsigned short As[2][128 * 64];
    __shared__ unsigned short Bs[2][128 * 64];

    const int tid  = threadIdx.x;
    const int bid  = blockIdx.x;
    const int mblk = bid & 15;
    const int nblk = bid >> 4;
    const int st_row = tid >> 3;
    const int st_g   = tid & 7;
    const int lane = tid & 63;
    const int wv   = tid >> 6;
    const int wm   = (wv >> 1) << 6;
    const int wn   = (wv & 1) << 6;
    const int l15  = lane & 15;
    const int l4   = lane >> 4;

    const float* aptr = A + (size_t)(mblk * 128 + st_row) * K_DIM + st_g * 8;
    const float* bptr = W + (size_t)(nblk * 128 + st_row) * K_DIM + st_g * 8;

    f32x4 acc[4][4] = {};
    float4 ra[4][2], rb[4][2];

    #pragma unroll
    for (int s = 0; s < 4; ++s) {
        const float* ap = aptr + (size_t)(s * 32) * K_DIM;
        const float* bp = bptr + (size_t)(s * 32) * K_DIM;
        ra[s][0] = *(const float4*)(ap);   ra[s][1] = *(const float4*)(ap + 4);
        rb[s][0] = *(const float4*)(bp);   rb[s][1] = *(const float4*)(bp + 4);
    }
    #pragma unroll
    for (int s = 0; s < 4; ++s) {
        const int row = s * 32 + st_row;
        const int off = row * 64 + ((st_g ^ (row & 7)) << 3);
        us8 pa, pb;
        #pragma unroll
        for (int j = 0; j < 4; ++j) {
            pa[j] = f2bf_rn(((const float*)&ra[s][0])[j]);
            pa[j + 4] = f2bf_rn(((const float*)&ra[s][1])[j]);
            pb[j] = f2bf_rn(((const float*)&rb[s][0])[j]);
            pb[j + 4] = f2bf_rn(((const float*)&rb[s][1])[j]);
        }
        *(us8*)&As[0][off] = pa;  *(us8*)&Bs[0][off] = pb;
    }
    __syncthreads();

    for (int t = 0; t < 64; ++t) {
        const int cur = t & 1;
        const bool more = (t + 1) < 64;
        if (more) {
            const float* ap = aptr + (size_t)(t + 1) * 64;
            const float* bp = bptr + (size_t)(t + 1) * 64;
            #pragma unroll
            for (int s = 0; s < 4; ++s) {
                ra[s][0] = *(const float4*)(ap + (size_t)(s * 32) * K_DIM);
                ra[s][1] = *(const float4*)(ap + (size_t)(s * 32) * K_DIM + 4);
                rb[s][0] = *(const float4*)(bp + (size_t)(s * 32) * K_DIM);
                rb[s][1] = *(const float4*)(bp + (size_t)(s * 32) * K_DIM + 4);
            }
        }
        const unsigned short* as = As[cur];
        const unsigned short* bs = Bs[cur];
        #pragma unroll
        for (int kk = 0; kk < 2; ++kk) {
            bhalf8 af[4], bfv[4];
            #pragma unroll
            for (int mf = 0; mf < 4; ++mf) {
                const int row = wm + mf * 16 + l15;
                af[mf] = *(const bhalf8*)&as[row * 64 + ((((kk << 2) + l4) ^ (row & 7)) << 3)];
            }
            #pragma unroll
            for (int nf = 0; nf < 4; ++nf) {
                const int row = wn + nf * 16 + l15;
                bfv[nf] = *(const bhalf8*)&bs[row * 64 + ((((kk << 2) + l4) ^ (row & 7)) << 3)];
            }
            #pragma unroll
            for (int mf = 0; mf < 4; ++mf)
                #pragma unroll
                for (int nf = 0; nf < 4; ++nf)
                    acc[mf][nf] = __builtin_amdgcn_mfma_f32_16x16x32_bf16(
                        af[mf], bfv[nf], acc[mf][nf], 0, 0, 0);
        }
        if (more) {
            const int nbuf = cur ^ 1;
            #pragma unroll
            for (int s = 0; s < 4; ++s) {
                const int row = s * 32 + st_row;
                const int off = row * 64 + ((st_g ^ (row & 7)) << 3);
                us8 pa, pb;
                #pragma unroll
                for (int j = 0; j < 4; ++j) {
                    pa[j] = f2bf_rn(((const float*)&ra[s][0])[j]);
                    pa[j + 4] = f2bf_rn(((const float*)&ra[s][1])[j]);
                    pb[j] = f2bf_rn(((const float*)&rb[s][0])[j]);
                    pb[j + 4] = f2bf_rn(((const float*)&rb[s][1])[j]);
                }
                *(us8*)&As[nbuf][off] = pa;  *(us8*)&Bs[nbuf][off] = pb;
            }
        }
        __syncthreads();
    }

    const size_t crow0 = (size_t)(mblk * 128 + wm + l4 * 4);
    const int    ccol0 = nblk * 128 + wn + l15;
    #pragma unroll
    for (int nf = 0; nf < 4; ++nf) {
        const float bv = bias[ccol0 + nf * 16];
        #pragma unroll
        for (int mf = 0; mf < 4; ++mf) {
            const size_t base = (crow0 + (size_t)mf * 16) * N_DIM + ccol0 + nf * 16;
            #pragma unroll
            for (int r = 0; r < 4; ++r)
                C[base + (size_t)r * N_DIM] = acc[mf][nf][r] + bv;
        }
    }
}

extern "C" void kernel_launch(void* const* d_in, const int* in_sizes, int n_in,
                              void* d_out, int out_size, void* d_ws, size_t ws_size,
                              hipStream_t stream) {
    const float* h = (const float*)d_in[0];
    const float* w = (const float*)d_in[1];
    const float* b = (const float*)d_in[2];
    float* out = (float*)d_out;
    // split_num (d_in[3]) is a semantic no-op: K-slices sum to the full GEMM.

    if (ws_size >= WS_NEEDED) {
        unsigned short* wbf = (unsigned short*)d_ws;
        unsigned short* hbf = wbf + W_ELEMS;
        cvt_f32_bf16<<<2048, 256, 0, stream>>>(w, wbf, W_ELEMS / 8);
        cvt_f32_bf16<<<512, 256, 0, stream>>>(h, hbf, H_ELEMS / 8);
        lmhead_gemm_256<<<NWG, 512, 0, stream>>>(hbf, wbf, b, out);
    } else {
        lmhead_gemm_f32<<<4000, 256, 0, stream>>>(h, w, b, out);
    }
}